// Round 1
// baseline (135.729 us; speedup 1.0000x reference)
//
#include <hip/hip_runtime.h>

#define IN_F 4096
#define OUT_F 4096
#define KGRP 16
#define N_ROWS (8 * 2048)

// ---------------------------------------------------------------------------
// Kernel 1: wsum[f] = sum_o weight[o][f], accumulated in double.
// Grid: (IN_F/256 col-blocks, 4096/64 row-blocks), 256 threads.
// Each thread owns one column f and sums 64 rows; coalesced (wave reads 64
// consecutive floats = 256B per instruction). One double atomicAdd per thread.
// ---------------------------------------------------------------------------
__global__ __launch_bounds__(256) void wsum_kernel(const float* __restrict__ w,
                                                   double* __restrict__ wsum) {
    const int f = blockIdx.x * 256 + threadIdx.x;
    const int r0 = blockIdx.y * 64;
    const float* p = w + (size_t)r0 * IN_F + f;
    double s = 0.0;
#pragma unroll 8
    for (int o = 0; o < 64; ++o) {
        s += (double)p[(size_t)o * IN_F];
    }
    atomicAdd(&wsum[f], s);
}

// ---------------------------------------------------------------------------
// Kernel 2: one block per row n.
// Phase A: 16 group dot-products g[k] = sum_{f in [256k,256k+256)} x[f]*wsum[f]
//   Load step k: thread t loads float4 at index k*256+t (contiguous 4KB/step).
//   float4 index k*256+t covers f = 4*(k*256+t).. +3, group = k*4 + (t>>6),
//   so all 64 lanes of a wave land in ONE group -> full-wave shfl_xor reduce.
// Phase B: thread 0 cumsums the 16 group sums, picks first prefix >= 0
//   (else the total), broadcasts S.
// Phase C: out[f] = sigmoid(S + bias[f]) with float4 stores.
// ---------------------------------------------------------------------------
__global__ __launch_bounds__(256) void sigmaif_kernel(const float* __restrict__ x,
                                                      const float* __restrict__ bias,
                                                      const double* __restrict__ wsum,
                                                      float* __restrict__ out) {
    const int n = blockIdx.x;
    const int t = threadIdx.x;
    const int wave = t >> 6;

    const float4* xr = (const float4*)(x + (size_t)n * IN_F);

    __shared__ double g[KGRP];
    __shared__ float Sbc;

    double part[4];
#pragma unroll
    for (int k = 0; k < 4; ++k) {
        float4 v = xr[k * 256 + t];
        const double* wp = &wsum[4 * (k * 256 + t)];
        double2 w01 = *(const double2*)(wp);
        double2 w23 = *(const double2*)(wp + 2);
        part[k] = (double)v.x * w01.x + (double)v.y * w01.y +
                  (double)v.z * w23.x + (double)v.w * w23.y;
    }

#pragma unroll
    for (int k = 0; k < 4; ++k) {
#pragma unroll
        for (int off = 32; off > 0; off >>= 1)
            part[k] += __shfl_xor(part[k], off, 64);
        if ((t & 63) == 0) g[k * 4 + wave] = part[k];
    }
    __syncthreads();

    if (t == 0) {
        double cs = 0.0, S = 0.0;
        bool found = false;
#pragma unroll
        for (int k = 0; k < KGRP; ++k) {
            cs += g[k];
            if (!found && cs >= 0.0) { S = cs; found = true; }
        }
        if (!found) S = cs;  // no prefix hit threshold -> take last (total)
        Sbc = (float)S;
    }
    __syncthreads();

    const float S = Sbc;
    const float4* b4 = (const float4*)bias;
    float4* o4 = (float4*)(out + (size_t)n * OUT_F);
#pragma unroll
    for (int k = 0; k < 4; ++k) {
        float4 b = b4[k * 256 + t];
        float4 r;
        r.x = 1.0f / (1.0f + __expf(-(S + b.x)));
        r.y = 1.0f / (1.0f + __expf(-(S + b.y)));
        r.z = 1.0f / (1.0f + __expf(-(S + b.z)));
        r.w = 1.0f / (1.0f + __expf(-(S + b.w)));
        o4[k * 256 + t] = r;
    }
}

extern "C" void kernel_launch(void* const* d_in, const int* in_sizes, int n_in,
                              void* d_out, int out_size, void* d_ws, size_t ws_size,
                              hipStream_t stream) {
    const float* x    = (const float*)d_in[0];   // [8,2048,4096] f32
    const float* w    = (const float*)d_in[1];   // [4096,4096]   f32
    const float* bias = (const float*)d_in[2];   // [4096]        f32
    float* out = (float*)d_out;                  // [8,2048,4096] f32
    double* wsum = (double*)d_ws;                // [4096] f64 scratch

    hipMemsetAsync(d_ws, 0, IN_F * sizeof(double), stream);

    dim3 g1(IN_F / 256, OUT_F / 64);
    wsum_kernel<<<g1, 256, 0, stream>>>(w, wsum);

    sigmaif_kernel<<<N_ROWS, 256, 0, stream>>>(x, bias, wsum, out);
}

// Round 3
// 122.264 us; speedup vs baseline: 1.1101x; 1.1101x over previous
//
#include <hip/hip_runtime.h>

#define IN_F 4096
#define OUT_F 4096
#define KGRP 16
#define N_ROWS (8 * 2048)

typedef float f32x4 __attribute__((ext_vector_type(4)));

// d_ws layout (all 16B-aligned):
//   [0,      32KB) : wsum    double[4096]
//   [32KB,   96KB) : S       float[16384]
//   [96KB,  608KB) : partial double[16][4096]

// ---------------------------------------------------------------------------
// Kernel 1a: partial column sums of weight, no atomics, no memset needed.
// grid (16 col-blocks, 16 row-blocks); each block sums 256 rows for 256 cols.
// Wave reads 64 consecutive floats per instruction (fully coalesced).
// ---------------------------------------------------------------------------
__global__ __launch_bounds__(256) void wsum_partial_kernel(const float* __restrict__ w,
                                                           double* __restrict__ partial) {
    const int f = blockIdx.x * 256 + threadIdx.x;
    const int r0 = blockIdx.y * 256;
    const float* p = w + (size_t)r0 * IN_F + f;
    double s = 0.0;
#pragma unroll 8
    for (int o = 0; o < 256; ++o) s += (double)p[(size_t)o * IN_F];
    partial[blockIdx.y * IN_F + f] = s;
}

// Kernel 1b: wsum[f] = sum over 16 partials. 16 blocks x 256 threads.
__global__ __launch_bounds__(256) void wsum_reduce_kernel(const double* __restrict__ partial,
                                                          double* __restrict__ wsum) {
    const int f = blockIdx.x * 256 + threadIdx.x;
    double s = 0.0;
#pragma unroll
    for (int p = 0; p < KGRP; ++p) s += partial[p * IN_F + f];
    wsum[f] = s;
}

// ---------------------------------------------------------------------------
// Kernel 2: pure-read. One block per row; compute scalar activation S[n].
//   Load step k: thread t loads float4 idx k*256+t; group = k*4 + (t>>6),
//   so each wave's 64 lanes land in one group -> full-wave shfl_xor reduce.
//   Double accumulation keeps the cs>=0 sign test essentially exact.
// ---------------------------------------------------------------------------
__global__ __launch_bounds__(256) void srow_kernel(const float* __restrict__ x,
                                                   const double* __restrict__ wsum,
                                                   float* __restrict__ S) {
    const int n = blockIdx.x;
    const int t = threadIdx.x;
    const int wave = t >> 6;
    const f32x4* xr = (const f32x4*)(x + (size_t)n * IN_F);

    __shared__ double g[KGRP];

    double part[4];
#pragma unroll
    for (int k = 0; k < 4; ++k) {
        f32x4 v = __builtin_nontemporal_load(&xr[k * 256 + t]);
        const double* wp = &wsum[4 * (k * 256 + t)];
        double2 w01 = *(const double2*)(wp);
        double2 w23 = *(const double2*)(wp + 2);
        part[k] = (double)v.x * w01.x + (double)v.y * w01.y +
                  (double)v.z * w23.x + (double)v.w * w23.y;
    }

#pragma unroll
    for (int k = 0; k < 4; ++k) {
#pragma unroll
        for (int off = 32; off > 0; off >>= 1)
            part[k] += __shfl_xor(part[k], off, 64);
        if ((t & 63) == 0) g[k * 4 + wave] = part[k];
    }
    __syncthreads();

    if (t == 0) {
        double cs = 0.0, Sv = 0.0;
        bool found = false;
#pragma unroll
        for (int k = 0; k < KGRP; ++k) {
            cs += g[k];
            if (!found && cs >= 0.0) { Sv = cs; found = true; }
        }
        if (!found) Sv = cs;  // no prefix >= 0 -> take total
        S[n] = (float)Sv;
    }
}

// ---------------------------------------------------------------------------
// Kernel 3: pure-write. out[n,f] = sigmoid(S[n] + bias[f]).
// One block per row; bias (16KB) is L1-resident after first block per CU.
// Nontemporal float4 stores (streaming, no reuse).
// ---------------------------------------------------------------------------
__global__ __launch_bounds__(256) void out_kernel(const float* __restrict__ S,
                                                  const float* __restrict__ bias,
                                                  float* __restrict__ out) {
    const int n = blockIdx.x;
    const int t = threadIdx.x;
    const float Sv = S[n];
    const f32x4* b4 = (const f32x4*)bias;
    f32x4* o4 = (f32x4*)(out + (size_t)n * OUT_F);
#pragma unroll
    for (int k = 0; k < 4; ++k) {
        f32x4 b = b4[k * 256 + t];
        f32x4 r;
        r.x = 1.0f / (1.0f + __expf(-(Sv + b.x)));
        r.y = 1.0f / (1.0f + __expf(-(Sv + b.y)));
        r.z = 1.0f / (1.0f + __expf(-(Sv + b.z)));
        r.w = 1.0f / (1.0f + __expf(-(Sv + b.w)));
        __builtin_nontemporal_store(r, &o4[k * 256 + t]);
    }
}

extern "C" void kernel_launch(void* const* d_in, const int* in_sizes, int n_in,
                              void* d_out, int out_size, void* d_ws, size_t ws_size,
                              hipStream_t stream) {
    const float* x    = (const float*)d_in[0];   // [8,2048,4096] f32
    const float* w    = (const float*)d_in[1];   // [4096,4096]   f32
    const float* bias = (const float*)d_in[2];   // [4096]        f32
    float* out = (float*)d_out;                  // [8,2048,4096] f32

    char* ws = (char*)d_ws;
    double* wsum    = (double*)(ws);                 // 4096 doubles
    float*  S       = (float*)(ws + 32 * 1024);      // 16384 floats
    double* partial = (double*)(ws + 96 * 1024);     // 16*4096 doubles

    dim3 g1(IN_F / 256, KGRP);
    wsum_partial_kernel<<<g1, 256, 0, stream>>>(w, partial);
    wsum_reduce_kernel<<<IN_F / 256, 256, 0, stream>>>(partial, wsum);
    srow_kernel<<<N_ROWS, 256, 0, stream>>>(x, wsum, S);
    out_kernel<<<N_ROWS, 256, 0, stream>>>(S, bias, out);
}

// Round 4
// 121.653 us; speedup vs baseline: 1.1157x; 1.0050x over previous
//
#include <hip/hip_runtime.h>

#define IN_F 4096
#define OUT_F 4096
#define KGRP 16
#define N_ROWS (8 * 2048)
#define RPB 8                      // rows per block for srow/out
#define NBLK (N_ROWS / RPB)        // 2048 blocks

typedef float f32x4 __attribute__((ext_vector_type(4)));

// d_ws layout (all 16B-aligned):
//   [0,      32KB) : wsum    double[4096]
//   [32KB,   96KB) : S       float[16384]
//   [96KB,  608KB) : partial double[16][4096]

// ---------------------------------------------------------------------------
// Kernel 1a: partial column sums of weight (no atomics). grid (16,16).
// ---------------------------------------------------------------------------
__global__ __launch_bounds__(256) void wsum_partial_kernel(const float* __restrict__ w,
                                                           double* __restrict__ partial) {
    const int f = blockIdx.x * 256 + threadIdx.x;
    const int r0 = blockIdx.y * 256;
    const float* p = w + (size_t)r0 * IN_F + f;
    double s = 0.0;
#pragma unroll 8
    for (int o = 0; o < 256; ++o) s += (double)p[(size_t)o * IN_F];
    partial[blockIdx.y * IN_F + f] = s;
}

// Kernel 1b: wsum[f] = sum over 16 partials.
__global__ __launch_bounds__(256) void wsum_reduce_kernel(const double* __restrict__ partial,
                                                          double* __restrict__ wsum) {
    const int f = blockIdx.x * 256 + threadIdx.x;
    double s = 0.0;
#pragma unroll
    for (int p = 0; p < KGRP; ++p) s += partial[p * IN_F + f];
    wsum[f] = s;
}

// ---------------------------------------------------------------------------
// Kernel 2: pure-read. 2048 blocks x 8 rows. wsum hoisted to registers once.
// Per row: 4 float4 nontemporal loads/thread, dot in double, full-wave
// shfl_xor reduce (group = k*4 + wave), lane0 -> LDS. No barrier inside the
// row loop (shfl is intra-wave), so the compiler overlaps row r+1 loads with
// row r's reduce chain. One barrier, then threads 0..7 cumsum 8 rows in
// parallel. Summation order identical to the R3 passing version.
// ---------------------------------------------------------------------------
__global__ __launch_bounds__(256) void srow_kernel(const float* __restrict__ x,
                                                   const double* __restrict__ wsum,
                                                   float* __restrict__ S) {
    const int t = threadIdx.x;
    const int wave = t >> 6;
    const int n0 = blockIdx.x * RPB;

    __shared__ double g[RPB][KGRP];

    double wreg[16];
#pragma unroll
    for (int k = 0; k < 4; ++k) {
        const double* wp = &wsum[4 * (k * 256 + t)];
        double2 w01 = *(const double2*)(wp);
        double2 w23 = *(const double2*)(wp + 2);
        wreg[4 * k + 0] = w01.x; wreg[4 * k + 1] = w01.y;
        wreg[4 * k + 2] = w23.x; wreg[4 * k + 3] = w23.y;
    }

    for (int r = 0; r < RPB; ++r) {
        const f32x4* xr = (const f32x4*)(x + (size_t)(n0 + r) * IN_F);
        double part[4];
#pragma unroll
        for (int k = 0; k < 4; ++k) {
            f32x4 v = __builtin_nontemporal_load(&xr[k * 256 + t]);
            part[k] = (double)v.x * wreg[4 * k + 0] + (double)v.y * wreg[4 * k + 1] +
                      (double)v.z * wreg[4 * k + 2] + (double)v.w * wreg[4 * k + 3];
        }
#pragma unroll
        for (int k = 0; k < 4; ++k) {
#pragma unroll
            for (int off = 32; off > 0; off >>= 1)
                part[k] += __shfl_xor(part[k], off, 64);
            if ((t & 63) == 0) g[r][k * 4 + wave] = part[k];
        }
    }
    __syncthreads();

    if (t < RPB) {
        double cs = 0.0, Sv = 0.0;
        bool found = false;
#pragma unroll
        for (int k = 0; k < KGRP; ++k) {
            cs += g[t][k];
            if (!found && cs >= 0.0) { Sv = cs; found = true; }
        }
        if (!found) Sv = cs;  // no prefix >= 0 -> take total
        S[n0 + t] = (float)Sv;
    }
}

// ---------------------------------------------------------------------------
// Kernel 3: pure-write. 2048 blocks x 8 rows; bias hoisted to registers once.
// sigmoid via hardware rcp (1-ulp; threshold 0.02).
// ---------------------------------------------------------------------------
__global__ __launch_bounds__(256) void out_kernel(const float* __restrict__ S,
                                                  const float* __restrict__ bias,
                                                  float* __restrict__ out) {
    const int t = threadIdx.x;
    const int n0 = blockIdx.x * RPB;
    const f32x4* b4 = (const f32x4*)bias;

    f32x4 b[4];
#pragma unroll
    for (int k = 0; k < 4; ++k) b[k] = b4[k * 256 + t];

    for (int r = 0; r < RPB; ++r) {
        const float Sv = S[n0 + r];
        f32x4* o4 = (f32x4*)(out + (size_t)(n0 + r) * OUT_F);
#pragma unroll
        for (int k = 0; k < 4; ++k) {
            f32x4 rr;
            rr.x = __builtin_amdgcn_rcpf(1.0f + __expf(-(Sv + b[k].x)));
            rr.y = __builtin_amdgcn_rcpf(1.0f + __expf(-(Sv + b[k].y)));
            rr.z = __builtin_amdgcn_rcpf(1.0f + __expf(-(Sv + b[k].z)));
            rr.w = __builtin_amdgcn_rcpf(1.0f + __expf(-(Sv + b[k].w)));
            __builtin_nontemporal_store(rr, &o4[k * 256 + t]);
        }
    }
}

extern "C" void kernel_launch(void* const* d_in, const int* in_sizes, int n_in,
                              void* d_out, int out_size, void* d_ws, size_t ws_size,
                              hipStream_t stream) {
    const float* x    = (const float*)d_in[0];   // [8,2048,4096] f32
    const float* w    = (const float*)d_in[1];   // [4096,4096]   f32
    const float* bias = (const float*)d_in[2];   // [4096]        f32
    float* out = (float*)d_out;                  // [8,2048,4096] f32

    char* ws = (char*)d_ws;
    double* wsum    = (double*)(ws);                 // 4096 doubles
    float*  S       = (float*)(ws + 32 * 1024);      // 16384 floats
    double* partial = (double*)(ws + 96 * 1024);     // 16*4096 doubles

    dim3 g1(IN_F / 256, KGRP);
    wsum_partial_kernel<<<g1, 256, 0, stream>>>(w, partial);
    wsum_reduce_kernel<<<IN_F / 256, 256, 0, stream>>>(partial, wsum);
    srow_kernel<<<NBLK, 256, 0, stream>>>(x, wsum, S);
    out_kernel<<<NBLK, 256, 0, stream>>>(S, bias, out);
}